// Round 2
// baseline (645.384 us; speedup 1.0000x reference)
//
#include <hip/hip_runtime.h>
#include <hip/hip_cooperative_groups.h>
#include <math.h>

namespace cg = cooperative_groups;

#define HID 1024
#define VOC 50257
#define MLEN 12
#define NBLK 256
#define NTHR 256

__device__ __forceinline__ float wave_xor_sum(float v) {
    for (int off = 32; off; off >>= 1) v += __shfl_xor(v, off, 64);
    return v;
}

__global__ __launch_bounds__(NTHR) void fused_decoder(
    const int* __restrict__ tok_p, const float* __restrict__ h0,
    const float* __restrict__ c0, const float* __restrict__ enc,
    const float* __restrict__ emb, const float* __restrict__ attn_W,
    const float* __restrict__ attn_b, const float* __restrict__ comb_W,
    const float* __restrict__ comb_b, const float* __restrict__ W_ih,
    const float* __restrict__ W_hh, const float* __restrict__ b_ih,
    const float* __restrict__ b_hh, const float* __restrict__ out_W,
    const float* __restrict__ out_b,
    float* __restrict__ out_logp, float* __restrict__ out_h,
    float* __restrict__ out_c, float* __restrict__ out_attnw,
    float* __restrict__ ws_x, float* __restrict__ ws_h,
    float* __restrict__ ws_pm, float* __restrict__ ws_ps,
    float* __restrict__ ws_lse)
{
    cg::grid_group grid = cg::this_grid();
    __shared__ float smem[2048];            // xin / {x,h0} / h  (reused per phase)
    __shared__ float s_log[MLEN], s_w[MLEN];
    __shared__ float rm[4], rs[4];
    const int t = threadIdx.x, wid = t >> 6, lane = t & 63;
    const int bid = blockIdx.x;
    const int gw = bid * 4 + wid;           // global wave id 0..1023

    const int tok = tok_p[0];               // int64 low word
    const float4* emb4 = (const float4*)(emb + (size_t)tok * HID);
    const float4* h04  = (const float4*)h0;

    // ---- Phase A: attention logits + softmax + attn_applied (redundant per block) ----
    {
        const float4* aW4 = (const float4*)attn_W;
        for (int l = wid; l < MLEN; l += 4) {
            float s = 0.f;
            for (int k = 0; k < 8; ++k) {
                int idx = k * 64 + lane;
                float4 v = (idx < 256) ? emb4[idx] : h04[idx - 256];
                float4 w = aW4[l * 512 + idx];
                s += v.x * w.x + v.y * w.y + v.z * w.z + v.w * w.w;
            }
            s = wave_xor_sum(s);
            if (lane == 0) s_log[l] = s + attn_b[l];
        }
    }
    __syncthreads();
    if (t == 0) {
        float m = -1e30f;
        for (int l = 0; l < MLEN; ++l) m = fmaxf(m, s_log[l]);
        float ss = 0.f;
        for (int l = 0; l < MLEN; ++l) { float e = expf(s_log[l] - m); s_w[l] = e; ss += e; }
        float inv = 1.f / ss;
        for (int l = 0; l < MLEN; ++l) {
            s_w[l] *= inv;
            if (bid == 0) out_attnw[l] = s_w[l];
        }
    }
    __syncthreads();
    {   // xin = [embedded, attn_applied] into LDS
        const float4* enc4 = (const float4*)enc;
        float4 e = emb4[t];
        float4 acc = make_float4(0.f, 0.f, 0.f, 0.f);
        for (int l = 0; l < MLEN; ++l) {
            float wl = s_w[l];
            float4 v = enc4[l * 256 + t];
            acc.x += wl * v.x; acc.y += wl * v.y; acc.z += wl * v.z; acc.w += wl * v.w;
        }
        float4* x4 = (float4*)smem;
        x4[t] = e;
        x4[256 + t] = acc;
    }
    __syncthreads();

    // ---- Phase B: x = relu(comb_W @ xin + b); one row per wave, 1024 waves ----
    {
        const int row = gw;
        const float4* W4 = (const float4*)(comb_W + (size_t)row * 2048);
        const float4* v4 = (const float4*)smem;
        float s = 0.f;
        for (int k = 0; k < 8; ++k) {
            int idx = k * 64 + lane;
            float4 w = W4[idx], v = v4[idx];
            s += w.x * v.x + w.y * v.y + w.z * v.z + w.w * v.w;
        }
        s = wave_xor_sum(s);
        if (lane == 0) ws_x[row] = fmaxf(s + comb_b[row], 0.f);
    }
    __threadfence();
    grid.sync();   // ---- sync 1 ----

    // ---- Phase C: gates + LSTM cell; wave handles hidden index gw ----
    {
        float4* x4 = (float4*)smem;
        x4[t]       = ((const float4*)ws_x)[t];  // x   -> smem[0..1023]
        x4[256 + t] = h04[t];                    // h0  -> smem[1024..2047]
    }
    __syncthreads();
    {
        const int h = gw;
        float g4[4];
        for (int g = 0; g < 4; ++g) {
            const int row = g * HID + h;
            const float4* Wi4 = (const float4*)(W_ih + (size_t)row * HID);
            const float4* Wh4 = (const float4*)(W_hh + (size_t)row * HID);
            const float4* x4  = (const float4*)smem;
            float s = 0.f;
            for (int k = 0; k < 4; ++k) {
                int idx = k * 64 + lane;
                float4 wi = Wi4[idx], xv = x4[idx];
                float4 wh = Wh4[idx], hv = x4[256 + idx];
                s += wi.x * xv.x + wi.y * xv.y + wi.z * xv.z + wi.w * xv.w;
                s += wh.x * hv.x + wh.y * hv.y + wh.z * hv.z + wh.w * hv.w;
            }
            s = wave_xor_sum(s);
            g4[g] = s + b_ih[row] + b_hh[row];
        }
        if (lane == 0) {
            float i = 1.f / (1.f + expf(-g4[0]));
            float f = 1.f / (1.f + expf(-g4[1]));
            float gg = tanhf(g4[2]);
            float o = 1.f / (1.f + expf(-g4[3]));
            float c = f * c0[h] + i * gg;
            float hh = o * tanhf(c);
            out_c[h] = c;
            out_h[h] = hh;
            ws_h[h] = hh;
        }
    }
    __threadfence();
    grid.sync();   // ---- sync 2 ----

    // ---- Phase D: logits = out_W @ h + b, with per-wave online LSE partials ----
    {
        float4* h4w = (float4*)smem;
        h4w[t] = ((const float4*)ws_h)[t];
    }
    __syncthreads();
    {
        const float4* h4 = (const float4*)smem;
        float m_run = -1e30f, s_run = 0.f;
        for (int r = gw; r < VOC; r += 2048) {
            const int r2 = r + 1024;
            const bool v2 = (r2 < VOC);
            const float4* Wa = (const float4*)(out_W + (size_t)r * HID);
            const float4* Wb = (const float4*)(out_W + (size_t)(v2 ? r2 : r) * HID);
            float sa = 0.f, sb = 0.f;
            for (int k = 0; k < 4; ++k) {
                int idx = k * 64 + lane;
                float4 hv = h4[idx];
                float4 wa = Wa[idx];
                sa += wa.x * hv.x + wa.y * hv.y + wa.z * hv.z + wa.w * hv.w;
                float4 wb = Wb[idx];
                sb += wb.x * hv.x + wb.y * hv.y + wb.z * hv.z + wb.w * hv.w;
            }
            sa = wave_xor_sum(sa);
            sb = wave_xor_sum(sb);
            sa += out_b[r];
            if (lane == 0) out_logp[r] = sa;
            float mn = fmaxf(m_run, sa);
            s_run = s_run * expf(m_run - mn) + expf(sa - mn);
            m_run = mn;
            if (v2) {
                sb += out_b[r2];
                if (lane == 0) out_logp[r2] = sb;
                mn = fmaxf(m_run, sb);
                s_run = s_run * expf(m_run - mn) + expf(sb - mn);
                m_run = mn;
            }
        }
        if (lane == 0) { ws_pm[gw] = m_run; ws_ps[gw] = s_run; }
    }
    __threadfence();
    grid.sync();   // ---- sync 3 ----

    // ---- Phase E: block 0 combines the 1024 (m,s) partials ----
    if (bid == 0) {
        float m = -1e30f, s = 0.f;
        for (int i = t; i < 1024; i += NTHR) {
            float pm = ws_pm[i], ps = ws_ps[i];
            float mn = fmaxf(m, pm);
            s = s * expf(m - mn) + ps * expf(pm - mn);
            m = mn;
        }
        for (int off = 32; off; off >>= 1) {
            float om = __shfl_xor(m, off, 64), os = __shfl_xor(s, off, 64);
            float mn = fmaxf(m, om);
            s = s * expf(m - mn) + os * expf(om - mn);
            m = mn;
        }
        if (lane == 0) { rm[wid] = m; rs[wid] = s; }
        __syncthreads();
        if (t == 0) {
            float M = rm[0], S = rs[0];
            for (int w = 1; w < 4; ++w) {
                float mn = fmaxf(M, rm[w]);
                S = S * expf(M - mn) + rs[w] * expf(rm[w] - mn);
                M = mn;
            }
            ws_lse[0] = M + logf(S);
        }
    }
    __threadfence();
    grid.sync();   // ---- sync 4 ----

    // ---- Phase F: logp = logits - lse ----
    {
        const float lse = ws_lse[0];
        const int i = bid * NTHR + t;
        if (i < VOC) out_logp[i] -= lse;
    }
}

extern "C" void kernel_launch(void* const* d_in, const int* in_sizes, int n_in,
                              void* d_out, int out_size, void* d_ws, size_t ws_size,
                              hipStream_t stream) {
    const int*   tok      = (const int*)d_in[0];
    const float* h_hidden = (const float*)d_in[1];
    const float* c_hidden = (const float*)d_in[2];
    const float* enc      = (const float*)d_in[3];
    const float* emb      = (const float*)d_in[4];
    const float* attn_W   = (const float*)d_in[5];
    const float* attn_b   = (const float*)d_in[6];
    const float* comb_W   = (const float*)d_in[7];
    const float* comb_b   = (const float*)d_in[8];
    const float* W_ih     = (const float*)d_in[9];
    const float* W_hh     = (const float*)d_in[10];
    const float* b_ih     = (const float*)d_in[11];
    const float* b_hh     = (const float*)d_in[12];
    const float* out_W    = (const float*)d_in[13];
    const float* out_b    = (const float*)d_in[14];

    float* out       = (float*)d_out;
    float* out_logp  = out;                       // [50257]
    float* out_h     = out + VOC;                 // [1024]
    float* out_c     = out + VOC + HID;           // [1024]
    float* out_attnw = out + VOC + 2 * HID;       // [12]

    float* ws     = (float*)d_ws;
    float* ws_x   = ws;                  // 1024 floats (16B aligned)
    float* ws_h   = ws + 1024;           // 1024
    float* ws_pm  = ws + 2048;           // 1024
    float* ws_ps  = ws + 3072;           // 1024
    float* ws_lse = ws + 4096;           // 1

    void* args[] = {
        (void*)&tok, (void*)&h_hidden, (void*)&c_hidden, (void*)&enc,
        (void*)&emb, (void*)&attn_W, (void*)&attn_b, (void*)&comb_W,
        (void*)&comb_b, (void*)&W_ih, (void*)&W_hh, (void*)&b_ih,
        (void*)&b_hh, (void*)&out_W, (void*)&out_b,
        (void*)&out_logp, (void*)&out_h, (void*)&out_c, (void*)&out_attnw,
        (void*)&ws_x, (void*)&ws_h, (void*)&ws_pm, (void*)&ws_ps, (void*)&ws_lse
    };
    hipLaunchCooperativeKernel((const void*)fused_decoder, dim3(NBLK), dim3(NTHR),
                               args, 0, stream);
}